// Round 2
// baseline (301.578 us; speedup 1.0000x reference)
//
#include <hip/hip_runtime.h>
#include <hip/hip_bf16.h>

typedef __attribute__((ext_vector_type(4))) float f32x4;
typedef __attribute__((ext_vector_type(8))) short bf16x8;

#define LOG2E 1.4426950408889634f

__device__ __forceinline__ unsigned short f2b(float f) {
  union { float f; unsigned u; } v; v.f = f;
  unsigned r = v.u + 0x7fffu + ((v.u >> 16) & 1u);
  return (unsigned short)(r >> 16);
}
__device__ __forceinline__ float b2f(unsigned short s) {
  union { unsigned u; float f; } v; v.u = ((unsigned)s) << 16;
  return v.f;
}

__device__ __forceinline__ void gload_lds16(const void* g, void* l) {
  __builtin_amdgcn_global_load_lds(
      (const __attribute__((address_space(1))) unsigned*)g,
      (__attribute__((address_space(3))) unsigned*)l, 16, 0, 0);
}

// ---------------- fp32 -> bf16 convert ----------------
__global__ __launch_bounds__(256) void k_cvt(const float* __restrict__ src,
                                             unsigned short* __restrict__ dst, int n4) {
  int i = blockIdx.x * 256 + threadIdx.x;
  if (i >= n4) return;
  float4 v = ((const float4*)src)[i];
  ushort4 o;
  o.x = f2b(v.x); o.y = f2b(v.y); o.z = f2b(v.z); o.w = f2b(v.w);
  ((ushort4*)dst)[i] = o;
}

// ---------------- 1536x1536 transpose fp32 -> bf16 ----------------
__global__ __launch_bounds__(256) void k_transpose(const float* __restrict__ src,
                                                   unsigned short* __restrict__ dst) {
  __shared__ float tile[64][65];
  const int tx = threadIdx.x & 63, ty = threadIdx.x >> 6;
  const int r0 = (blockIdx.x / 24) * 64, c0 = (blockIdx.x % 24) * 64;
#pragma unroll
  for (int j = 0; j < 16; ++j)
    tile[ty + j * 4][tx] = src[(size_t)(r0 + ty + j * 4) * 1536 + c0 + tx];
  __syncthreads();
#pragma unroll
  for (int j = 0; j < 16; ++j)
    dst[(size_t)(c0 + ty + j * 4) * 1536 + r0 + tx] = f2b(tile[tx][ty + j * 4]);
}

// ---------------- bf16 GEMM: C = A(MxK) * BT(NxK)^T ----------------
// m97 pattern: 128x128 tile, BK=32, 256 threads (4 waves 2x2), linear LDS,
// global_load_lds width 16.
template <int OUTBF16>
__global__ __launch_bounds__(256) void k_gemm(const unsigned short* __restrict__ A,
                                              const unsigned short* __restrict__ BT,
                                              void* __restrict__ C,
                                              const float* __restrict__ bias,
                                              int M, int N, int K, int gridN) {
  __shared__ unsigned short As[128 * 32];
  __shared__ unsigned short Bs[128 * 32];
  const int tid = threadIdx.x;
  const int lane = tid & 63, wave = tid >> 6;
  const int bm = (blockIdx.x / gridN) * 128;
  const int bn = (blockIdx.x % gridN) * 128;
  const int wr = (wave >> 1) * 64, wc = (wave & 1) * 64;
  const int r15 = lane & 15, g = lane >> 4;
  const int row0 = tid >> 2, c0 = tid & 3;  // chunk L=tid ; i=1 -> row0+64

  f32x4 acc[4][4] = {};

  for (int k0 = 0; k0 < K; k0 += 32) {
    __syncthreads();
    gload_lds16(A + (size_t)(bm + row0) * K + k0 + c0 * 8, (char*)As + wave * 1024);
    gload_lds16(A + (size_t)(bm + row0 + 64) * K + k0 + c0 * 8,
                (char*)As + 4096 + wave * 1024);
    gload_lds16(BT + (size_t)(bn + row0) * K + k0 + c0 * 8, (char*)Bs + wave * 1024);
    gload_lds16(BT + (size_t)(bn + row0 + 64) * K + k0 + c0 * 8,
                (char*)Bs + 4096 + wave * 1024);
    __syncthreads();
    bf16x8 af[4], bfr[4];
#pragma unroll
    for (int m = 0; m < 4; ++m) {
      af[m] = *(const bf16x8*)&As[(wr + m * 16 + r15) * 32 + g * 8];
      bfr[m] = *(const bf16x8*)&Bs[(wc + m * 16 + r15) * 32 + g * 8];
    }
#pragma unroll
    for (int m = 0; m < 4; ++m)
#pragma unroll
      for (int n = 0; n < 4; ++n)
        acc[m][n] = __builtin_amdgcn_mfma_f32_16x16x32_bf16(af[m], bfr[n], acc[m][n], 0, 0, 0);
  }

#pragma unroll
  for (int m = 0; m < 4; ++m)
#pragma unroll
    for (int n = 0; n < 4; ++n)
#pragma unroll
      for (int i = 0; i < 4; ++i) {
        int row = bm + wr + m * 16 + g * 4 + i;
        int col = bn + wc + n * 16 + r15;
        float v = acc[m][n][i];
        if (OUTBF16)
          ((unsigned short*)C)[(size_t)row * N + col] = f2b(v);
        else
          ((float*)C)[(size_t)row * N + col] = v + bias[col];
      }
}

// ---------------- K/V low-rank injection (RMW on bf16 K,V) ----------------
__global__ __launch_bounds__(256) void k_inject(const float* __restrict__ Mm,
                                                const float* __restrict__ Wr,
                                                const float* __restrict__ Fk,
                                                const float* __restrict__ Fv,
                                                unsigned short* __restrict__ qkv) {
  __shared__ float Ml[256];
  __shared__ float gl[4];
  const int bid = blockIdx.x;  // 4096 = B(2)*H(8)*T(4)*NB(64)
  const int nb = bid & 63, t = (bid >> 6) & 3, h = (bid >> 8) & 7, b = bid >> 11;
  const int tid = threadIdx.x;
  const int nl = tid >> 6, d = tid & 63;
  Ml[tid] = Mm[(size_t)(((b * 4 + t) * 256 + nb * 4) * 64) + tid];
  if (tid < 4) gl[tid] = Wr[(b * 4 + t) * 256 + nb * 4 + tid];
  __syncthreads();
  float ak = 0.f, av = 0.f;
#pragma unroll 8
  for (int f = 0; f < 64; ++f) {
    float mv = Ml[nl * 64 + f];
    ak += mv * Fk[(h * 64 + f) * 64 + d];
    av += mv * Fv[(h * 64 + f) * 64 + d];
  }
  float gate = gl[nl];
  ak *= gate; av *= gate;
  const int n = nb * 4 + nl;
  const size_t s0 = (size_t)(b * 2048 + t * 256 + n);
#pragma unroll
  for (int r = 0; r < 2; ++r) {
    size_t row = s0 + (size_t)r * 1024;
    size_t ik = row * 4608 + 1536 + h * 64 + d;
    qkv[ik] = f2b(b2f(qkv[ik]) + ak);
    size_t iv = row * 4608 + 3072 + h * 64 + d;
    qkv[iv] = f2b(b2f(qkv[iv]) + av);
  }
}

// ---------------- flash attention, swapped QK^T ----------------
// 512 threads (8 waves), QBLK=128 (16 q rows/wave), KVBLK=64.
// K: LDS [64][64] linear, 16B-chunk XOR swizzle (source-pre-swizzled gload).
// V: staged transposed VT[d][kv] (+8 pad), plain reg writes.
// P: per-wave LDS round-trip (no cross-lane shuffle repack).
__global__ __launch_bounds__(512) void k_attn(const unsigned short* __restrict__ qkv,
                                              unsigned short* __restrict__ attno) {
  __shared__ unsigned short Kl[64 * 64];
  __shared__ unsigned short VT[64 * 72];
  __shared__ unsigned short Pl[8][16 * 72];
  const int tid = threadIdx.x;
  const int lane = tid & 63, wave = tid >> 6;
  const int bid = blockIdx.x;  // 768 = B*24*16
  const int qt = bid & 15;
  const int h = (bid >> 4) % 24;
  const int b = (bid >> 4) / 24;
  const int r15 = lane & 15, g = lane >> 4, sw7 = lane & 7;
  const int q0 = qt * 128 + wave * 16;
  const size_t RS = 4608;
  const size_t tokbase = (size_t)(b * 2048);

  // Q fragment (MFMA B-operand for S^T = K*Q^T), pre-scaled by 1/sqrt(64)=0.125 (exact)
  bf16x8 qb[2];
  {
    const unsigned short* qrow = qkv + (tokbase + q0 + r15) * RS + h * 64;
#pragma unroll
    for (int kk = 0; kk < 2; ++kk) {
      bf16x8 v = *(const bf16x8*)(qrow + kk * 32 + g * 8);
#pragma unroll
      for (int e = 0; e < 8; ++e)
        v[e] = (short)f2b(b2f((unsigned short)v[e]) * 0.125f);
      qb[kk] = v;
    }
  }

  f32x4 o[4] = {};
  float m_run = -1e30f, l_run = 0.0f;

  const int krow = tid >> 3, kc = tid & 7;
  const int ksc = kc ^ (krow & 7);  // XOR swizzle: byte ^= (row&7)<<4

  for (int kv0 = 0; kv0 < 2048; kv0 += 64) {
    __syncthreads();
    // K tile via global_load_lds (linear dest chunk=tid, pre-swizzled source)
    gload_lds16(qkv + (tokbase + kv0 + krow) * RS + 1536 + h * 64 + ksc * 8,
                (char*)Kl + wave * 1024);
    // V tile: reg-staged transpose. kv = lane, d0 = wave*8.
    bf16x8 vv = *(const bf16x8*)(qkv + (tokbase + kv0 + lane) * RS + 3072 + h * 64 + wave * 8);
#pragma unroll
    for (int e = 0; e < 8; ++e)
      VT[(wave * 8 + e) * 72 + lane] = (unsigned short)vv[e];
    __syncthreads();

    // S^T[kv][q] = K * Q^T, 4 row-blocks of 16 kv
    f32x4 st[4];
#pragma unroll
    for (int m = 0; m < 4; ++m) {
      int row = m * 16 + r15;
      bf16x8 ka0 = *(const bf16x8*)&Kl[row * 64 + ((g ^ sw7) * 8)];
      bf16x8 ka1 = *(const bf16x8*)&Kl[row * 64 + (((g + 4) ^ sw7) * 8)];
      f32x4 z = {0.f, 0.f, 0.f, 0.f};
      st[m] = __builtin_amdgcn_mfma_f32_16x16x32_bf16(ka0, qb[0], z, 0, 0, 0);
      st[m] = __builtin_amdgcn_mfma_f32_16x16x32_bf16(ka1, qb[1], st[m], 0, 0, 0);
    }

    // online softmax; stats for q=r15 are lane-local, reduce across 4 kv-groups
    float pm = st[0][0];
#pragma unroll
    for (int m = 0; m < 4; ++m)
#pragma unroll
      for (int i = 0; i < 4; ++i) pm = fmaxf(pm, st[m][i]);
    pm = fmaxf(pm, __shfl_xor(pm, 16, 64));
    pm = fmaxf(pm, __shfl_xor(pm, 32, 64));
    float mnew = fmaxf(m_run, pm);
    float fac = exp2f((m_run - mnew) * LOG2E);
    float psum = 0.f;
#pragma unroll
    for (int m = 0; m < 4; ++m) {
      float p0 = exp2f((st[m][0] - mnew) * LOG2E);
      float p1 = exp2f((st[m][1] - mnew) * LOG2E);
      float p2 = exp2f((st[m][2] - mnew) * LOG2E);
      float p3 = exp2f((st[m][3] - mnew) * LOG2E);
      psum += (p0 + p1) + (p2 + p3);
      uint2 w2;
      w2.x = (unsigned)f2b(p0) | ((unsigned)f2b(p1) << 16);
      w2.y = (unsigned)f2b(p2) | ((unsigned)f2b(p3) << 16);
      *(uint2*)&Pl[wave][r15 * 72 + m * 16 + g * 4] = w2;  // P[q=r15][kv=m*16+g*4+i]
    }
    psum += __shfl_xor(psum, 16, 64);
    psum += __shfl_xor(psum, 32, 64);
    l_run = l_run * fac + psum;
    m_run = mnew;

    // rescale O (O rows are q' = 4g+i; factor lives in lanes with r15 = q')
    float f_i[4];
#pragma unroll
    for (int i = 0; i < 4; ++i)
      f_i[i] = __shfl(fac, (lane & 48) | ((((lane >> 4) & 3) << 2) + i), 64);
#pragma unroll
    for (int dt = 0; dt < 4; ++dt)
#pragma unroll
      for (int i = 0; i < 4; ++i) o[dt][i] *= f_i[i];

    // PV: A = P[q][kv] from per-wave LDS, B = V[kv][d] from VT
#pragma unroll
    for (int kap = 0; kap < 2; ++kap) {
      bf16x8 pa = *(const bf16x8*)&Pl[wave][r15 * 72 + kap * 32 + g * 8];
#pragma unroll
      for (int dt = 0; dt < 4; ++dt) {
        bf16x8 vb = *(const bf16x8*)&VT[(dt * 16 + r15) * 72 + kap * 32 + g * 8];
        o[dt] = __builtin_amdgcn_mfma_f32_16x16x32_bf16(pa, vb, o[dt], 0, 0, 0);
      }
    }
  }

  // epilogue: O /= l
  float rl = 1.0f / l_run;
  float r_i[4];
#pragma unroll
  for (int i = 0; i < 4; ++i)
    r_i[i] = __shfl(rl, (lane & 48) | ((((lane >> 4) & 3) << 2) + i), 64);
#pragma unroll
  for (int dt = 0; dt < 4; ++dt)
#pragma unroll
    for (int i = 0; i < 4; ++i) {
      int q = q0 + ((lane >> 4) << 2) + i;
      int col = h * 64 + dt * 16 + r15;
      attno[(tokbase + q) * 1536 + col] = f2b(o[dt][i] * r_i[i]);
    }
}

extern "C" void kernel_launch(void* const* d_in, const int* in_sizes, int n_in,
                              void* d_out, int out_size, void* d_ws, size_t ws_size,
                              hipStream_t stream) {
  const float* hs = (const float*)d_in[0];
  const float* Wq = (const float*)d_in[1];
  const float* Wk = (const float*)d_in[2];
  const float* Wv = (const float*)d_in[3];
  const float* Wo = (const float*)d_in[4];
  const float* bo = (const float*)d_in[5];
  const float* Mm = (const float*)d_in[6];
  const float* Wr = (const float*)d_in[7];
  const float* Fk = (const float*)d_in[8];
  const float* Fv = (const float*)d_in[9];
  float* out = (float*)d_out;

  // workspace (bf16), ~61.5 MiB total with aliasing:
  //   hsb   [4096*1536]  -> reused as attno after gemm1
  //   wqkvt [4608*1536]  -> reused as wot after gemm1
  //   qkv   [4096*4608]
  unsigned short* hsb   = (unsigned short*)d_ws;
  unsigned short* wqkvt = hsb + (size_t)4096 * 1536;
  unsigned short* qkv   = wqkvt + (size_t)4608 * 1536;
  unsigned short* attno = hsb;
  unsigned short* wot   = wqkvt;

  k_cvt<<<6144, 256, 0, stream>>>(hs, hsb, 1572864);
  k_transpose<<<576, 256, 0, stream>>>(Wq, wqkvt);
  k_transpose<<<576, 256, 0, stream>>>(Wk, wqkvt + (size_t)1536 * 1536);
  k_transpose<<<576, 256, 0, stream>>>(Wv, wqkvt + (size_t)3072 * 1536);

  k_gemm<1><<<32 * 36, 256, 0, stream>>>(hsb, wqkvt, (void*)qkv, (const float*)nullptr,
                                         4096, 4608, 1536, 36);
  k_transpose<<<576, 256, 0, stream>>>(Wo, wot);  // after gemm1: wot aliases wqkvt
  k_inject<<<4096, 256, 0, stream>>>(Mm, Wr, Fk, Fv, qkv);
  k_attn<<<768, 512, 0, stream>>>(qkv, attno);    // attno aliases hsb
  k_gemm<0><<<32 * 12, 256, 0, stream>>>(attno, wot, (void*)out, bo, 4096, 1536, 1536, 12);
}

// Round 3
// 264.361 us; speedup vs baseline: 1.1408x; 1.1408x over previous
//
#include <hip/hip_runtime.h>
#include <hip/hip_bf16.h>

typedef __attribute__((ext_vector_type(4))) float f32x4;
typedef __attribute__((ext_vector_type(8))) short bf16x8;

#define LOG2E 1.4426950408889634f

__device__ __forceinline__ unsigned short f2b(float f) {
  union { float f; unsigned u; } v; v.f = f;
  unsigned r = v.u + 0x7fffu + ((v.u >> 16) & 1u);
  return (unsigned short)(r >> 16);
}
__device__ __forceinline__ float b2f(unsigned short s) {
  union { unsigned u; float f; } v; v.u = ((unsigned)s) << 16;
  return v.f;
}
// packed f32x2 -> bf16x2 (RNE), low word = lo
__device__ __forceinline__ unsigned cvtpk(float lo, float hi) {
  unsigned r;
  asm("v_cvt_pk_bf16_f32 %0, %1, %2" : "=v"(r) : "v"(lo), "v"(hi));
  return r;
}
// raw 2^x
__device__ __forceinline__ float fexp2(float x) {
  float r;
  asm("v_exp_f32 %0, %1" : "=v"(r) : "v"(x));
  return r;
}

__device__ __forceinline__ void gload_lds16(const void* g, void* l) {
  __builtin_amdgcn_global_load_lds(
      (const __attribute__((address_space(1))) unsigned*)g,
      (__attribute__((address_space(3))) unsigned*)l, 16, 0, 0);
}

// ---------------- fp32 -> bf16 convert ----------------
__global__ __launch_bounds__(256) void k_cvt(const float* __restrict__ src,
                                             unsigned short* __restrict__ dst, int n4) {
  int i = blockIdx.x * 256 + threadIdx.x;
  if (i >= n4) return;
  float4 v = ((const float4*)src)[i];
  ushort4 o;
  o.x = f2b(v.x); o.y = f2b(v.y); o.z = f2b(v.z); o.w = f2b(v.w);
  ((ushort4*)dst)[i] = o;
}

// ---------------- 1536x1536 transpose fp32 -> bf16 ----------------
__global__ __launch_bounds__(256) void k_transpose(const float* __restrict__ src,
                                                   unsigned short* __restrict__ dst) {
  __shared__ float tile[64][65];
  const int tx = threadIdx.x & 63, ty = threadIdx.x >> 6;
  const int r0 = (blockIdx.x / 24) * 64, c0 = (blockIdx.x % 24) * 64;
#pragma unroll
  for (int j = 0; j < 16; ++j)
    tile[ty + j * 4][tx] = src[(size_t)(r0 + ty + j * 4) * 1536 + c0 + tx];
  __syncthreads();
#pragma unroll
  for (int j = 0; j < 16; ++j)
    dst[(size_t)(c0 + ty + j * 4) * 1536 + r0 + tx] = f2b(tile[tx][ty + j * 4]);
}

// ---------------- bf16 GEMM: C = A(MxK) * BT(NxK)^T ----------------
// m97 pattern: 128x128 tile, BK=32, 256 threads (4 waves 2x2), linear LDS,
// global_load_lds width 16.
template <int OUTBF16>
__global__ __launch_bounds__(256) void k_gemm(const unsigned short* __restrict__ A,
                                              const unsigned short* __restrict__ BT,
                                              void* __restrict__ C,
                                              const float* __restrict__ bias,
                                              int M, int N, int K, int gridN) {
  __shared__ unsigned short As[128 * 32];
  __shared__ unsigned short Bs[128 * 32];
  const int tid = threadIdx.x;
  const int lane = tid & 63, wave = tid >> 6;
  const int bm = (blockIdx.x / gridN) * 128;
  const int bn = (blockIdx.x % gridN) * 128;
  const int wr = (wave >> 1) * 64, wc = (wave & 1) * 64;
  const int r15 = lane & 15, g = lane >> 4;
  const int row0 = tid >> 2, c0 = tid & 3;  // chunk L=tid ; i=1 -> row0+64

  f32x4 acc[4][4] = {};

  for (int k0 = 0; k0 < K; k0 += 32) {
    __syncthreads();
    gload_lds16(A + (size_t)(bm + row0) * K + k0 + c0 * 8, (char*)As + wave * 1024);
    gload_lds16(A + (size_t)(bm + row0 + 64) * K + k0 + c0 * 8,
                (char*)As + 4096 + wave * 1024);
    gload_lds16(BT + (size_t)(bn + row0) * K + k0 + c0 * 8, (char*)Bs + wave * 1024);
    gload_lds16(BT + (size_t)(bn + row0 + 64) * K + k0 + c0 * 8,
                (char*)Bs + 4096 + wave * 1024);
    __syncthreads();
    bf16x8 af[4], bfr[4];
#pragma unroll
    for (int m = 0; m < 4; ++m) {
      af[m] = *(const bf16x8*)&As[(wr + m * 16 + r15) * 32 + g * 8];
      bfr[m] = *(const bf16x8*)&Bs[(wc + m * 16 + r15) * 32 + g * 8];
    }
#pragma unroll
    for (int m = 0; m < 4; ++m)
#pragma unroll
      for (int n = 0; n < 4; ++n)
        acc[m][n] = __builtin_amdgcn_mfma_f32_16x16x32_bf16(af[m], bfr[n], acc[m][n], 0, 0, 0);
  }

#pragma unroll
  for (int m = 0; m < 4; ++m)
#pragma unroll
    for (int n = 0; n < 4; ++n)
#pragma unroll
      for (int i = 0; i < 4; ++i) {
        int row = bm + wr + m * 16 + g * 4 + i;
        int col = bn + wc + n * 16 + r15;
        float v = acc[m][n][i];
        if (OUTBF16)
          ((unsigned short*)C)[(size_t)row * N + col] = f2b(v);
        else
          ((float*)C)[(size_t)row * N + col] = v + bias[col];
      }
}

// ---------------- K/V low-rank injection (RMW on bf16 K,V) ----------------
__global__ __launch_bounds__(256) void k_inject(const float* __restrict__ Mm,
                                                const float* __restrict__ Wr,
                                                const float* __restrict__ Fk,
                                                const float* __restrict__ Fv,
                                                unsigned short* __restrict__ qkv) {
  __shared__ float Ml[256];
  __shared__ float gl[4];
  const int bid = blockIdx.x;  // 4096 = B(2)*H(8)*T(4)*NB(64)
  const int nb = bid & 63, t = (bid >> 6) & 3, h = (bid >> 8) & 7, b = bid >> 11;
  const int tid = threadIdx.x;
  const int nl = tid >> 6, d = tid & 63;
  Ml[tid] = Mm[(size_t)(((b * 4 + t) * 256 + nb * 4) * 64) + tid];
  if (tid < 4) gl[tid] = Wr[(b * 4 + t) * 256 + nb * 4 + tid];
  __syncthreads();
  float ak = 0.f, av = 0.f;
#pragma unroll 8
  for (int f = 0; f < 64; ++f) {
    float mv = Ml[nl * 64 + f];
    ak += mv * Fk[(h * 64 + f) * 64 + d];
    av += mv * Fv[(h * 64 + f) * 64 + d];
  }
  float gate = gl[nl];
  ak *= gate; av *= gate;
  const int n = nb * 4 + nl;
  const size_t s0 = (size_t)(b * 2048 + t * 256 + n);
#pragma unroll
  for (int r = 0; r < 2; ++r) {
    size_t row = s0 + (size_t)r * 1024;
    size_t ik = row * 4608 + 1536 + h * 64 + d;
    qkv[ik] = f2b(b2f(qkv[ik]) + ak);
    size_t iv = row * 4608 + 3072 + h * 64 + d;
    qkv[iv] = f2b(b2f(qkv[iv]) + av);
  }
}

// ---------------- flash attention, swapped QK^T ----------------
// 512 threads (8 waves), QBLK=128 (16 q rows/wave), KVBLK=64.
// Scores computed in log2 domain (Q prescaled by 0.125*LOG2E).
// P->bf16 via v_cvt_pk_bf16_f32; defer-max (THR=8, log2) skips O-rescale.
__global__ __launch_bounds__(512) void k_attn(const unsigned short* __restrict__ qkv,
                                              unsigned short* __restrict__ attno) {
  __shared__ unsigned short Kl[64 * 64];
  __shared__ unsigned short VT[64 * 72];
  __shared__ unsigned short Pl[8][16 * 72];
  const int tid = threadIdx.x;
  const int lane = tid & 63, wave = tid >> 6;
  const int bid = blockIdx.x;  // 768 = B*24*16
  const int qt = bid & 15;
  const int h = (bid >> 4) % 24;
  const int b = (bid >> 4) / 24;
  const int r15 = lane & 15, g = lane >> 4, sw7 = lane & 7;
  const int q0 = qt * 128 + wave * 16;
  const size_t RS = 4608;
  const size_t tokbase = (size_t)(b * 2048);

  // Q fragment (MFMA B-operand for S^T = K*Q^T), pre-scaled by 0.125*log2(e)
  // so all softmax math runs in the log2 domain (exp -> raw v_exp_f32).
  bf16x8 qb[2];
  {
    const unsigned short* qrow = qkv + (tokbase + q0 + r15) * RS + h * 64;
    const float qs = 0.125f * LOG2E;
#pragma unroll
    for (int kk = 0; kk < 2; ++kk) {
      bf16x8 v = *(const bf16x8*)(qrow + kk * 32 + g * 8);
#pragma unroll
      for (int e = 0; e < 8; ++e)
        v[e] = (short)f2b(b2f((unsigned short)v[e]) * qs);
      qb[kk] = v;
    }
  }

  f32x4 o[4] = {};
  float m_run = -1e30f, l_run = 0.0f;

  const int krow = tid >> 3, kc = tid & 7;
  const int ksc = kc ^ (krow & 7);  // XOR swizzle: byte ^= (row&7)<<4

  for (int kv0 = 0; kv0 < 2048; kv0 += 64) {
    __syncthreads();
    // K tile via global_load_lds (linear dest chunk=tid, pre-swizzled source)
    gload_lds16(qkv + (tokbase + kv0 + krow) * RS + 1536 + h * 64 + ksc * 8,
                (char*)Kl + wave * 1024);
    // V tile: reg-staged transpose. kv = lane, d0 = wave*8.
    bf16x8 vv = *(const bf16x8*)(qkv + (tokbase + kv0 + lane) * RS + 3072 + h * 64 + wave * 8);
#pragma unroll
    for (int e = 0; e < 8; ++e)
      VT[(wave * 8 + e) * 72 + lane] = (unsigned short)vv[e];
    __syncthreads();

    // S^T[kv][q] = K * Q^T, 4 row-blocks of 16 kv (log2-domain scores)
    f32x4 st[4];
    __builtin_amdgcn_s_setprio(1);
#pragma unroll
    for (int m = 0; m < 4; ++m) {
      int row = m * 16 + r15;
      bf16x8 ka0 = *(const bf16x8*)&Kl[row * 64 + ((g ^ sw7) * 8)];
      bf16x8 ka1 = *(const bf16x8*)&Kl[row * 64 + (((g + 4) ^ sw7) * 8)];
      f32x4 z = {0.f, 0.f, 0.f, 0.f};
      st[m] = __builtin_amdgcn_mfma_f32_16x16x32_bf16(ka0, qb[0], z, 0, 0, 0);
      st[m] = __builtin_amdgcn_mfma_f32_16x16x32_bf16(ka1, qb[1], st[m], 0, 0, 0);
    }
    __builtin_amdgcn_s_setprio(0);

    // per-q (q=r15) max across this tile, reduced over the 4 kv-groups
    float pm = fmaxf(fmaxf(fmaxf(st[0][0], st[0][1]), fmaxf(st[0][2], st[0][3])),
                     fmaxf(fmaxf(st[1][0], st[1][1]), fmaxf(st[1][2], st[1][3])));
    pm = fmaxf(pm,
               fmaxf(fmaxf(fmaxf(st[2][0], st[2][1]), fmaxf(st[2][2], st[2][3])),
                     fmaxf(fmaxf(st[3][0], st[3][1]), fmaxf(st[3][2], st[3][3]))));
    pm = fmaxf(pm, __shfl_xor(pm, 16, 64));
    pm = fmaxf(pm, __shfl_xor(pm, 32, 64));

    // defer-max: only rescale when the running max grew by > 8 (log2 domain;
    // P values stay <= 2^8 = 256, safe in bf16/f32)
    if (!__all(pm - m_run <= 8.0f)) {
      float mnew = fmaxf(m_run, pm);
      float fac = fexp2(m_run - mnew);
      l_run *= fac;
      float f_i[4];
#pragma unroll
      for (int i = 0; i < 4; ++i)
        f_i[i] = __shfl(fac, (lane & 48) | ((((lane >> 4) & 3) << 2) + i), 64);
#pragma unroll
      for (int dt = 0; dt < 4; ++dt)
#pragma unroll
        for (int i = 0; i < 4; ++i) o[dt][i] *= f_i[i];
      m_run = mnew;
    }

    // P = 2^(st - m_run); pack to bf16 pairs via v_cvt_pk_bf16_f32
    float psum = 0.f;
#pragma unroll
    for (int m = 0; m < 4; ++m) {
      float p0 = fexp2(st[m][0] - m_run);
      float p1 = fexp2(st[m][1] - m_run);
      float p2 = fexp2(st[m][2] - m_run);
      float p3 = fexp2(st[m][3] - m_run);
      psum += (p0 + p1) + (p2 + p3);
      uint2 w2;
      w2.x = cvtpk(p0, p1);
      w2.y = cvtpk(p2, p3);
      *(uint2*)&Pl[wave][r15 * 72 + m * 16 + g * 4] = w2;  // P[q=r15][kv=m*16+g*4+i]
    }
    psum += __shfl_xor(psum, 16, 64);
    psum += __shfl_xor(psum, 32, 64);
    l_run += psum;

    // PV: A = P[q][kv] from per-wave LDS, B = V[kv][d] from VT
    __builtin_amdgcn_s_setprio(1);
#pragma unroll
    for (int kap = 0; kap < 2; ++kap) {
      bf16x8 pa = *(const bf16x8*)&Pl[wave][r15 * 72 + kap * 32 + g * 8];
#pragma unroll
      for (int dt = 0; dt < 4; ++dt) {
        bf16x8 vb = *(const bf16x8*)&VT[(dt * 16 + r15) * 72 + kap * 32 + g * 8];
        o[dt] = __builtin_amdgcn_mfma_f32_16x16x32_bf16(pa, vb, o[dt], 0, 0, 0);
      }
    }
    __builtin_amdgcn_s_setprio(0);
  }

  // epilogue: O /= l
  float rl = 1.0f / l_run;
  float r_i[4];
#pragma unroll
  for (int i = 0; i < 4; ++i)
    r_i[i] = __shfl(rl, (lane & 48) | ((((lane >> 4) & 3) << 2) + i), 64);
#pragma unroll
  for (int dt = 0; dt < 4; ++dt)
#pragma unroll
    for (int i = 0; i < 4; ++i) {
      int q = q0 + ((lane >> 4) << 2) + i;
      int col = h * 64 + dt * 16 + r15;
      attno[(tokbase + q) * 1536 + col] = f2b(o[dt][i] * r_i[i]);
    }
}

extern "C" void kernel_launch(void* const* d_in, const int* in_sizes, int n_in,
                              void* d_out, int out_size, void* d_ws, size_t ws_size,
                              hipStream_t stream) {
  const float* hs = (const float*)d_in[0];
  const float* Wq = (const float*)d_in[1];
  const float* Wk = (const float*)d_in[2];
  const float* Wv = (const float*)d_in[3];
  const float* Wo = (const float*)d_in[4];
  const float* bo = (const float*)d_in[5];
  const float* Mm = (const float*)d_in[6];
  const float* Wr = (const float*)d_in[7];
  const float* Fk = (const float*)d_in[8];
  const float* Fv = (const float*)d_in[9];
  float* out = (float*)d_out;

  // workspace (bf16), ~61.5 MiB total with aliasing:
  //   hsb   [4096*1536]  -> reused as attno after gemm1
  //   wqkvt [4608*1536]  -> reused as wot after gemm1
  //   qkv   [4096*4608]
  unsigned short* hsb   = (unsigned short*)d_ws;
  unsigned short* wqkvt = hsb + (size_t)4096 * 1536;
  unsigned short* qkv   = wqkvt + (size_t)4608 * 1536;
  unsigned short* attno = hsb;
  unsigned short* wot   = wqkvt;

  k_cvt<<<6144, 256, 0, stream>>>(hs, hsb, 1572864);
  k_transpose<<<576, 256, 0, stream>>>(Wq, wqkvt);
  k_transpose<<<576, 256, 0, stream>>>(Wk, wqkvt + (size_t)1536 * 1536);
  k_transpose<<<576, 256, 0, stream>>>(Wv, wqkvt + (size_t)3072 * 1536);

  k_gemm<1><<<32 * 36, 256, 0, stream>>>(hsb, wqkvt, (void*)qkv, (const float*)nullptr,
                                         4096, 4608, 1536, 36);
  k_transpose<<<576, 256, 0, stream>>>(Wo, wot);  // after gemm1: wot aliases wqkvt
  k_inject<<<4096, 256, 0, stream>>>(Mm, Wr, Fk, Fv, qkv);
  k_attn<<<768, 512, 0, stream>>>(qkv, attno);    // attno aliases hsb
  k_gemm<0><<<32 * 12, 256, 0, stream>>>(attno, wot, (void*)out, bo, 4096, 1536, 1536, 12);
}

// Round 4
// 252.331 us; speedup vs baseline: 1.1952x; 1.0477x over previous
//
#include <hip/hip_runtime.h>
#include <hip/hip_bf16.h>

typedef __attribute__((ext_vector_type(4))) float f32x4;
typedef __attribute__((ext_vector_type(8))) short bf16x8;

#define LOG2E 1.4426950408889634f

__device__ __forceinline__ unsigned short f2b(float f) {
  union { float f; unsigned u; } v; v.f = f;
  unsigned r = v.u + 0x7fffu + ((v.u >> 16) & 1u);
  return (unsigned short)(r >> 16);
}
__device__ __forceinline__ float b2f(unsigned short s) {
  union { unsigned u; float f; } v; v.u = ((unsigned)s) << 16;
  return v.f;
}
// packed f32x2 -> bf16x2 (RNE), low word = lo
__device__ __forceinline__ unsigned cvtpk(float lo, float hi) {
  unsigned r;
  asm("v_cvt_pk_bf16_f32 %0, %1, %2" : "=v"(r) : "v"(lo), "v"(hi));
  return r;
}
// raw 2^x
__device__ __forceinline__ float fexp2(float x) {
  float r;
  asm("v_exp_f32 %0, %1" : "=v"(r) : "v"(x));
  return r;
}

__device__ __forceinline__ void gload_lds16(const void* g, void* l) {
  __builtin_amdgcn_global_load_lds(
      (const __attribute__((address_space(1))) unsigned*)g,
      (__attribute__((address_space(3))) unsigned*)l, 16, 0, 0);
}

// ---------------- fp32 -> bf16 convert ----------------
__global__ __launch_bounds__(256) void k_cvt(const float* __restrict__ src,
                                             unsigned short* __restrict__ dst, int n4) {
  int i = blockIdx.x * 256 + threadIdx.x;
  if (i >= n4) return;
  float4 v = ((const float4*)src)[i];
  ushort4 o;
  o.x = f2b(v.x); o.y = f2b(v.y); o.z = f2b(v.z); o.w = f2b(v.w);
  ((ushort4*)dst)[i] = o;
}

// ---------------- 1536x1536 transpose fp32 -> bf16 (x3 batched) ----------------
__global__ __launch_bounds__(256) void k_transpose3(const float* __restrict__ s0,
                                                    const float* __restrict__ s1,
                                                    const float* __restrict__ s2,
                                                    unsigned short* __restrict__ dst) {
  __shared__ float tile[64][65];
  const int which = blockIdx.x / 576;
  const int bid = blockIdx.x % 576;
  const float* src = which == 0 ? s0 : (which == 1 ? s1 : s2);
  unsigned short* d = dst + (size_t)which * 1536 * 1536;
  const int tx = threadIdx.x & 63, ty = threadIdx.x >> 6;
  const int r0 = (bid / 24) * 64, c0 = (bid % 24) * 64;
#pragma unroll
  for (int j = 0; j < 16; ++j)
    tile[ty + j * 4][tx] = src[(size_t)(r0 + ty + j * 4) * 1536 + c0 + tx];
  __syncthreads();
#pragma unroll
  for (int j = 0; j < 16; ++j)
    d[(size_t)(c0 + ty + j * 4) * 1536 + r0 + tx] = f2b(tile[tx][ty + j * 4]);
}

__global__ __launch_bounds__(256) void k_transpose(const float* __restrict__ src,
                                                   unsigned short* __restrict__ dst) {
  __shared__ float tile[64][65];
  const int tx = threadIdx.x & 63, ty = threadIdx.x >> 6;
  const int r0 = (blockIdx.x / 24) * 64, c0 = (blockIdx.x % 24) * 64;
#pragma unroll
  for (int j = 0; j < 16; ++j)
    tile[ty + j * 4][tx] = src[(size_t)(r0 + ty + j * 4) * 1536 + c0 + tx];
  __syncthreads();
#pragma unroll
  for (int j = 0; j < 16; ++j)
    dst[(size_t)(c0 + ty + j * 4) * 1536 + r0 + tx] = f2b(tile[tx][ty + j * 4]);
}

// ---------------- bf16 GEMM: C = A(MxK) * BT(NxK)^T ----------------
// m97 pattern: 128x128 tile, BK=32, 256 threads (4 waves 2x2), linear LDS,
// global_load_lds width 16.
template <int OUTBF16>
__global__ __launch_bounds__(256) void k_gemm(const unsigned short* __restrict__ A,
                                              const unsigned short* __restrict__ BT,
                                              void* __restrict__ C,
                                              const float* __restrict__ bias,
                                              int M, int N, int K, int gridN) {
  __shared__ unsigned short As[128 * 32];
  __shared__ unsigned short Bs[128 * 32];
  const int tid = threadIdx.x;
  const int lane = tid & 63, wave = tid >> 6;
  const int bm = (blockIdx.x / gridN) * 128;
  const int bn = (blockIdx.x % gridN) * 128;
  const int wr = (wave >> 1) * 64, wc = (wave & 1) * 64;
  const int r15 = lane & 15, g = lane >> 4;
  const int row0 = tid >> 2, c0 = tid & 3;

  f32x4 acc[4][4] = {};

  for (int k0 = 0; k0 < K; k0 += 32) {
    __syncthreads();
    gload_lds16(A + (size_t)(bm + row0) * K + k0 + c0 * 8, (char*)As + wave * 1024);
    gload_lds16(A + (size_t)(bm + row0 + 64) * K + k0 + c0 * 8,
                (char*)As + 4096 + wave * 1024);
    gload_lds16(BT + (size_t)(bn + row0) * K + k0 + c0 * 8, (char*)Bs + wave * 1024);
    gload_lds16(BT + (size_t)(bn + row0 + 64) * K + k0 + c0 * 8,
                (char*)Bs + 4096 + wave * 1024);
    __syncthreads();
    bf16x8 af[4], bfr[4];
#pragma unroll
    for (int m = 0; m < 4; ++m) {
      af[m] = *(const bf16x8*)&As[(wr + m * 16 + r15) * 32 + g * 8];
      bfr[m] = *(const bf16x8*)&Bs[(wc + m * 16 + r15) * 32 + g * 8];
    }
#pragma unroll
    for (int m = 0; m < 4; ++m)
#pragma unroll
      for (int n = 0; n < 4; ++n)
        acc[m][n] = __builtin_amdgcn_mfma_f32_16x16x32_bf16(af[m], bfr[n], acc[m][n], 0, 0, 0);
  }

#pragma unroll
  for (int m = 0; m < 4; ++m)
#pragma unroll
    for (int n = 0; n < 4; ++n)
#pragma unroll
      for (int i = 0; i < 4; ++i) {
        int row = bm + wr + m * 16 + g * 4 + i;
        int col = bn + wc + n * 16 + r15;
        float v = acc[m][n][i];
        if (OUTBF16)
          ((unsigned short*)C)[(size_t)row * N + col] = f2b(v);
        else
          ((float*)C)[(size_t)row * N + col] = v + bias[col];
      }
}

// ---------------- K/V low-rank injection (RMW on bf16 K,V) ----------------
__global__ __launch_bounds__(256) void k_inject(const float* __restrict__ Mm,
                                                const float* __restrict__ Wr,
                                                const float* __restrict__ Fk,
                                                const float* __restrict__ Fv,
                                                unsigned short* __restrict__ qkv) {
  __shared__ float Ml[256];
  __shared__ float gl[4];
  const int bid = blockIdx.x;  // 4096 = B(2)*H(8)*T(4)*NB(64)
  const int nb = bid & 63, t = (bid >> 6) & 3, h = (bid >> 8) & 7, b = bid >> 11;
  const int tid = threadIdx.x;
  const int nl = tid >> 6, d = tid & 63;
  Ml[tid] = Mm[(size_t)(((b * 4 + t) * 256 + nb * 4) * 64) + tid];
  if (tid < 4) gl[tid] = Wr[(b * 4 + t) * 256 + nb * 4 + tid];
  __syncthreads();
  float ak = 0.f, av = 0.f;
#pragma unroll 8
  for (int f = 0; f < 64; ++f) {
    float mv = Ml[nl * 64 + f];
    ak += mv * Fk[(h * 64 + f) * 64 + d];
    av += mv * Fv[(h * 64 + f) * 64 + d];
  }
  float gate = gl[nl];
  ak *= gate; av *= gate;
  const int n = nb * 4 + nl;
  const size_t s0 = (size_t)(b * 2048 + t * 256 + n);
#pragma unroll
  for (int r = 0; r < 2; ++r) {
    size_t row = s0 + (size_t)r * 1024;
    size_t ik = row * 4608 + 1536 + h * 64 + d;
    qkv[ik] = f2b(b2f(qkv[ik]) + ak);
    size_t iv = row * 4608 + 3072 + h * 64 + d;
    qkv[iv] = f2b(b2f(qkv[iv]) + av);
  }
}

// ---------------- flash attention, swapped QK^T ----------------
// 256 threads (4 waves), each wave owns 32 q rows; KVBLK=64.
// Double-buffered K (XOR-swizzled, gload_lds) + VT (reg-staged transpose,
// T14 late-write). One barrier per iteration. Log2-domain softmax,
// cvt_pk P-pack, defer-max.
__global__ __launch_bounds__(256, 3) void k_attn(const unsigned short* __restrict__ qkv,
                                                 unsigned short* __restrict__ attno) {
  __shared__ unsigned short Kl[2 * 64 * 64];   // 16 KB
  __shared__ unsigned short VT[2 * 64 * 72];   // 18 KB
  __shared__ unsigned short Pl[4 * 32 * 72];   // 18 KB
  const int tid = threadIdx.x;
  const int lane = tid & 63, wave = tid >> 6;
  const int bid = blockIdx.x;  // 768 = B*24*16
  const int qt = bid & 15;
  const int h = (bid >> 4) % 24;
  const int b = (bid >> 4) / 24;
  const int r15 = lane & 15, g = lane >> 4;
  const int q0 = qt * 128 + wave * 32;
  const size_t RS = 4608;
  const size_t tokbase = (size_t)(b * 2048);
  unsigned short* Plw = Pl + wave * 32 * 72;

  // Q fragments (B-operand for S^T = K*Q^T), scaled by 0.125*log2(e)
  bf16x8 qb[2][2];  // [qh][kk]
  {
    const float qs = 0.125f * LOG2E;
#pragma unroll
    for (int qh = 0; qh < 2; ++qh) {
      const unsigned short* qrow = qkv + (tokbase + q0 + qh * 16 + r15) * RS + h * 64;
#pragma unroll
      for (int kk = 0; kk < 2; ++kk) {
        bf16x8 v = *(const bf16x8*)(qrow + kk * 32 + g * 8);
#pragma unroll
        for (int e = 0; e < 8; ++e)
          v[e] = (short)f2b(b2f((unsigned short)v[e]) * qs);
        qb[qh][kk] = v;
      }
    }
  }

  f32x4 o[2][4] = {};  // [qh][dt]
  float m_run[2] = {-1e30f, -1e30f}, l_run[2] = {0.f, 0.f};
  bf16x8 vr[2];

  // K stage: 2 gload_lds per wave; chunk = (wave*2+i)*64 + lane
  const int ch0 = wave * 2 * 64 + lane, ch1 = (wave * 2 + 1) * 64 + lane;
  const int kr0 = ch0 >> 3, kc0s = ((ch0 & 7) ^ (kr0 & 7)) * 8;
  const int kr1 = ch1 >> 3, kc1s = ((ch1 & 7) ^ (kr1 & 7)) * 8;

#define STAGE_K(buf, kv0)                                                          \
  {                                                                                \
    gload_lds16(qkv + (tokbase + (kv0) + kr0) * RS + 1536 + h * 64 + kc0s,         \
                (char*)Kl + (buf) * 8192 + (wave * 2) * 1024);                     \
    gload_lds16(qkv + (tokbase + (kv0) + kr1) * RS + 1536 + h * 64 + kc1s,         \
                (char*)Kl + (buf) * 8192 + (wave * 2 + 1) * 1024);                 \
  }
#define LOAD_V(kv0)                                                                \
  {                                                                                \
    const unsigned short* vrow = qkv + (tokbase + (kv0) + lane) * RS + 3072 + h * 64; \
    vr[0] = *(const bf16x8*)(vrow + (wave * 2) * 8);                               \
    vr[1] = *(const bf16x8*)(vrow + (wave * 2 + 1) * 8);                           \
  }
#define WRITE_V(buf)                                                               \
  {                                                                                \
    _Pragma("unroll") for (int s = 0; s < 2; ++s) {                                \
      int d0 = (wave * 2 + s) * 8;                                                 \
      _Pragma("unroll") for (int e = 0; e < 8; ++e)                                \
          VT[(buf) * 4608 + (d0 + e) * 72 + lane] = (unsigned short)vr[s][e];      \
    }                                                                              \
  }

  STAGE_K(0, 0);
  LOAD_V(0);
  asm volatile("s_waitcnt vmcnt(0)" ::: "memory");
  WRITE_V(0);
  __syncthreads();

  int cur = 0;
  for (int t = 0; t < 32; ++t) {
    const int kv0 = t * 64;
    if (t < 31) {
      STAGE_K(cur ^ 1, kv0 + 64);
      LOAD_V(kv0 + 64);
    }

    // S^T[kv][q] = K * Q^T  (4 kv-blocks x 2 q-halves, log2-domain)
    f32x4 st[4][2];
    const unsigned short* Kb = Kl + cur * 4096;
    __builtin_amdgcn_s_setprio(1);
#pragma unroll
    for (int m = 0; m < 4; ++m) {
      int row = m * 16 + r15;
      int r7 = row & 7;
      bf16x8 ka0 = *(const bf16x8*)&Kb[row * 64 + ((g ^ r7) * 8)];
      bf16x8 ka1 = *(const bf16x8*)&Kb[row * 64 + (((4 + g) ^ r7) * 8)];
#pragma unroll
      for (int qh = 0; qh < 2; ++qh) {
        f32x4 z = {0.f, 0.f, 0.f, 0.f};
        st[m][qh] = __builtin_amdgcn_mfma_f32_16x16x32_bf16(ka0, qb[qh][0], z, 0, 0, 0);
        st[m][qh] = __builtin_amdgcn_mfma_f32_16x16x32_bf16(ka1, qb[qh][1], st[m][qh], 0, 0, 0);
      }
    }
    __builtin_amdgcn_s_setprio(0);

    // per-q max (q = qh*16 + r15), reduce over 4 kv-groups (lanes xor 16,32)
    float pm[2];
#pragma unroll
    for (int qh = 0; qh < 2; ++qh) {
      float p = fmaxf(fmaxf(fmaxf(st[0][qh][0], st[0][qh][1]), fmaxf(st[0][qh][2], st[0][qh][3])),
                      fmaxf(fmaxf(st[1][qh][0], st[1][qh][1]), fmaxf(st[1][qh][2], st[1][qh][3])));
      p = fmaxf(p,
                fmaxf(fmaxf(fmaxf(st[2][qh][0], st[2][qh][1]), fmaxf(st[2][qh][2], st[2][qh][3])),
                      fmaxf(fmaxf(st[3][qh][0], st[3][qh][1]), fmaxf(st[3][qh][2], st[3][qh][3]))));
      p = fmaxf(p, __shfl_xor(p, 16, 64));
      pm[qh] = fmaxf(p, __shfl_xor(p, 32, 64));
    }

    // defer-max: rescale only when running max grew by > 8 (log2 domain)
    if (!__all(pm[0] - m_run[0] <= 8.0f && pm[1] - m_run[1] <= 8.0f)) {
#pragma unroll
      for (int qh = 0; qh < 2; ++qh) {
        float mnew = fmaxf(m_run[qh], pm[qh]);
        float fac = fexp2(m_run[qh] - mnew);
        l_run[qh] *= fac;
        float f_i[4];
#pragma unroll
        for (int i = 0; i < 4; ++i)
          f_i[i] = __shfl(fac, (lane & 48) | ((((lane >> 4) & 3) << 2) + i), 64);
#pragma unroll
        for (int dt = 0; dt < 4; ++dt)
#pragma unroll
          for (int i = 0; i < 4; ++i) o[qh][dt][i] *= f_i[i];
        m_run[qh] = mnew;
      }
    }

    // P = 2^(st - m); pack bf16 pairs; write to per-wave P tile
    float psum[2] = {0.f, 0.f};
#pragma unroll
    for (int m = 0; m < 4; ++m)
#pragma unroll
      for (int qh = 0; qh < 2; ++qh) {
        float p0 = fexp2(st[m][qh][0] - m_run[qh]);
        float p1 = fexp2(st[m][qh][1] - m_run[qh]);
        float p2 = fexp2(st[m][qh][2] - m_run[qh]);
        float p3 = fexp2(st[m][qh][3] - m_run[qh]);
        psum[qh] += (p0 + p1) + (p2 + p3);
        uint2 w2;
        w2.x = cvtpk(p0, p1);
        w2.y = cvtpk(p2, p3);
        *(uint2*)&Plw[(qh * 16 + r15) * 72 + m * 16 + g * 4] = w2;
      }
#pragma unroll
    for (int qh = 0; qh < 2; ++qh) {
      psum[qh] += __shfl_xor(psum[qh], 16, 64);
      psum[qh] += __shfl_xor(psum[qh], 32, 64);
      l_run[qh] += psum[qh];
    }

    // PV: A = P[q][kv], B = V[kv][d] from VT[cur]
    const unsigned short* Vb = VT + cur * 4608;
    __builtin_amdgcn_s_setprio(1);
#pragma unroll
    for (int kap = 0; kap < 2; ++kap) {
      bf16x8 pa0 = *(const bf16x8*)&Plw[(r15) * 72 + kap * 32 + g * 8];
      bf16x8 pa1 = *(const bf16x8*)&Plw[(16 + r15) * 72 + kap * 32 + g * 8];
#pragma unroll
      for (int dt = 0; dt < 4; ++dt) {
        bf16x8 vb = *(const bf16x8*)&Vb[(dt * 16 + r15) * 72 + kap * 32 + g * 8];
        o[0][dt] = __builtin_amdgcn_mfma_f32_16x16x32_bf16(pa0, vb, o[0][dt], 0, 0, 0);
        o[1][dt] = __builtin_amdgcn_mfma_f32_16x16x32_bf16(pa1, vb, o[1][dt], 0, 0, 0);
      }
    }
    __builtin_amdgcn_s_setprio(0);

    if (t < 31) {
      asm volatile("s_waitcnt vmcnt(0)" ::: "memory");
      WRITE_V(cur ^ 1);
    }
    __syncthreads();
    cur ^= 1;
  }

  // epilogue: O /= l
#pragma unroll
  for (int qh = 0; qh < 2; ++qh) {
    float rl = 1.0f / l_run[qh];
    float r_i[4];
#pragma unroll
    for (int i = 0; i < 4; ++i)
      r_i[i] = __shfl(rl, (lane & 48) | ((((lane >> 4) & 3) << 2) + i), 64);
#pragma unroll
    for (int dt = 0; dt < 4; ++dt)
#pragma unroll
      for (int i = 0; i < 4; ++i) {
        int q = q0 + qh * 16 + ((lane >> 4) << 2) + i;
        int col = h * 64 + dt * 16 + r15;
        attno[(tokbase + q) * 1536 + col] = f2b(o[qh][dt][i] * r_i[i]);
      }
  }
}

extern "C" void kernel_launch(void* const* d_in, const int* in_sizes, int n_in,
                              void* d_out, int out_size, void* d_ws, size_t ws_size,
                              hipStream_t stream) {
  const float* hs = (const float*)d_in[0];
  const float* Wq = (const float*)d_in[1];
  const float* Wk = (const float*)d_in[2];
  const float* Wv = (const float*)d_in[3];
  const float* Wo = (const float*)d_in[4];
  const float* bo = (const float*)d_in[5];
  const float* Mm = (const float*)d_in[6];
  const float* Wr = (const float*)d_in[7];
  const float* Fk = (const float*)d_in[8];
  const float* Fv = (const float*)d_in[9];
  float* out = (float*)d_out;

  // workspace (bf16), ~61.5 MiB total with aliasing:
  //   hsb   [4096*1536]  -> reused as attno after gemm1
  //   wqkvt [4608*1536]  -> reused as wot after gemm1
  //   qkv   [4096*4608]
  unsigned short* hsb   = (unsigned short*)d_ws;
  unsigned short* wqkvt = hsb + (size_t)4096 * 1536;
  unsigned short* qkv   = wqkvt + (size_t)4608 * 1536;
  unsigned short* attno = hsb;
  unsigned short* wot   = wqkvt;

  k_cvt<<<6144, 256, 0, stream>>>(hs, hsb, 1572864);
  k_transpose3<<<1728, 256, 0, stream>>>(Wq, Wk, Wv, wqkvt);

  k_gemm<1><<<32 * 36, 256, 0, stream>>>(hsb, wqkvt, (void*)qkv, (const float*)nullptr,
                                         4096, 4608, 1536, 36);
  k_transpose<<<576, 256, 0, stream>>>(Wo, wot);  // after gemm1: wot aliases wqkvt
  k_inject<<<4096, 256, 0, stream>>>(Mm, Wr, Fk, Fv, qkv);
  k_attn<<<768, 256, 0, stream>>>(qkv, attno);    // attno aliases hsb
  k_gemm<0><<<32 * 12, 256, 0, stream>>>(attno, wot, (void*)out, bo, 4096, 1536, 1536, 12);
}